// Round 1
// baseline (144.687 us; speedup 1.0000x reference)
//
#include <hip/hip_runtime.h>
#include <hip/hip_bf16.h>

#define NFEA 128
#define NCLS 5
#define LN_EPS 1e-5f

// One block per crystal: segment-mean pool -> LayerNorm -> softplus -> 5-way head.
// 256 threads = 8 atom-lanes x 32 float4 feature-chunks (16B/lane coalesced loads).
__global__ __launch_bounds__(256) void crys_fea_kernel(
    const float* __restrict__ fea,      // [N_ATOMS][128]
    const int2*  __restrict__ idx,      // [N_CRYS] (start, end)
    const float* __restrict__ lnw,      // [128]
    const float* __restrict__ lnb,      // [128]
    const float* __restrict__ outw,     // [5][128]
    const float* __restrict__ outb,     // [5]
    float* __restrict__ out_cls,        // [N_CRYS][5]   (output 0)
    float* __restrict__ out_act)        // [N_CRYS][128] (output 1)
{
    const int c = blockIdx.x;
    const int2 se = idx[c];
    const int start = se.x;
    const int end   = se.y;
    const int len   = end - start;

    const int tid = threadIdx.x;
    const int fc  = tid & 31;   // float4 feature chunk 0..31
    const int al  = tid >> 5;   // atom lane 0..7

    // --- segment sum (vectorized, coalesced) ---
    float4 acc = make_float4(0.f, 0.f, 0.f, 0.f);
    const float4* __restrict__ fea4 = (const float4*)fea;  // 32 float4 per row
    for (int a = start + al; a < end; a += 8) {
        float4 v = fea4[(size_t)a * 32 + fc];
        acc.x += v.x; acc.y += v.y; acc.z += v.z; acc.w += v.w;
    }

    __shared__ float4 red4[8][32];     // 4 KB, float4-stride = conflict-free
    red4[al][fc] = acc;
    __syncthreads();

    __shared__ float pooled[NFEA];
    __shared__ float s_mu, s_rstd;

    if (tid < NFEA) {
        const float* redf = (const float*)red4;  // [8][128]
        float s = 0.f;
        #pragma unroll
        for (int g = 0; g < 8; ++g) s += redf[g * NFEA + tid];
        pooled[tid] = s / (float)len;
    }
    __syncthreads();

    // --- LayerNorm stats: two-pass, one 64-lane wave ---
    if (tid < 64) {
        float v = pooled[tid] + pooled[tid + 64];
        #pragma unroll
        for (int off = 32; off; off >>= 1) v += __shfl_down(v, off);
        if (tid == 0) s_mu = v * (1.f / NFEA);
    }
    __syncthreads();
    if (tid < 64) {
        const float mu = s_mu;
        const float d0 = pooled[tid] - mu;
        const float d1 = pooled[tid + 64] - mu;
        float v = d0 * d0 + d1 * d1;
        #pragma unroll
        for (int off = 32; off; off >>= 1) v += __shfl_down(v, off);
        if (tid == 0) s_rstd = rsqrtf(v * (1.f / NFEA) + LN_EPS);
    }
    __syncthreads();

    // --- normalize + softplus, write act ---
    __shared__ float s_act[NFEA];
    if (tid < NFEA) {
        const float x = (pooled[tid] - s_mu) * s_rstd * lnw[tid] + lnb[tid];
        // numerically stable softplus: log1p(exp(x))
        const float a = (x > 0.f) ? (x + log1pf(expf(-x))) : log1pf(expf(x));
        s_act[tid] = a;
        out_act[(size_t)c * NFEA + tid] = a;
    }
    __syncthreads();

    // --- head: 5 dot products of length 128 (one wave) ---
    if (tid < 64) {
        const float a0 = s_act[tid];
        const float a1 = s_act[tid + 64];
        #pragma unroll
        for (int k = 0; k < NCLS; ++k) {
            float p = a0 * outw[k * NFEA + tid] + a1 * outw[k * NFEA + tid + 64];
            #pragma unroll
            for (int off = 32; off; off >>= 1) p += __shfl_down(p, off);
            if (tid == 0) out_cls[(size_t)c * NCLS + k] = p + outb[k];
        }
    }
}

extern "C" void kernel_launch(void* const* d_in, const int* in_sizes, int n_in,
                              void* d_out, int out_size, void* d_ws, size_t ws_size,
                              hipStream_t stream) {
    const float* fea  = (const float*)d_in[0];   // [1048576][128] f32
    const int2*  idx  = (const int2*)d_in[1];    // [8192][2] i32
    const float* lnw  = (const float*)d_in[2];   // [128]
    const float* lnb  = (const float*)d_in[3];   // [128]
    const float* outw = (const float*)d_in[4];   // [5][128]
    const float* outb = (const float*)d_in[5];   // [5]

    const int n_crys = in_sizes[1] / 2;          // 8192

    float* out_cls = (float*)d_out;                            // 8192*5
    float* out_act = (float*)d_out + (size_t)n_crys * NCLS;    // 8192*128

    crys_fea_kernel<<<n_crys, 256, 0, stream>>>(
        fea, idx, lnw, lnb, outw, outb, out_cls, out_act);
}

// Round 2
// 123.804 us; speedup vs baseline: 1.1687x; 1.1687x over previous
//
#include <hip/hip_runtime.h>
#include <hip/hip_bf16.h>

#define NFEA 128
#define NCLS 5
#define LN_EPS 1e-5f
#define CHUNK 128   // atoms per block in the partial-sum kernel

// Kernel A: perfectly load-balanced segment partial sums.
// Each block owns a fixed slab of CHUNK atoms, splits it at segment
// boundaries (avg ~2 runs/slab), and atomicAdds 128-float partials.
// 256 threads = 8 atom-lanes x 32 float4 feature-chunks.
__global__ __launch_bounds__(256) void seg_partial_kernel(
    const float* __restrict__ fea,      // [N_ATOMS][128]
    const int2*  __restrict__ idx,      // [N_CRYS] (start, end)
    float* __restrict__ seg_sum,        // [N_CRYS][128] (pre-zeroed ws)
    int n_crys)
{
    const int a0 = blockIdx.x * CHUNK;
    const int a1 = a0 + CHUNK;          // N_ATOMS is a multiple of CHUNK

    // largest s with idx[s].x <= a0 (starts are sorted, cover [0, N_ATOMS))
    int lo = 0, hi = n_crys - 1;
    while (lo < hi) {
        int mid = (lo + hi + 1) >> 1;
        if (idx[mid].x <= a0) lo = mid; else hi = mid - 1;
    }
    int s = lo;

    const int tid = threadIdx.x;
    const int fc  = tid & 31;   // float4 chunk within the 128-feature row
    const int al  = tid >> 5;   // atom lane 0..7

    const float4* __restrict__ fea4 = (const float4*)fea;
    __shared__ float4 red4[8][32];

    int rs = a0;
    while (rs < a1) {                       // uniform across the block
        const int re = min(idx[s].y, a1);   // run = this segment ∩ slab

        // 2-wide unrolled cooperative sum of [rs, re)
        float4 acc0 = make_float4(0.f, 0.f, 0.f, 0.f);
        float4 acc1 = make_float4(0.f, 0.f, 0.f, 0.f);
        int a = rs + al;
        for (; a + 8 < re; a += 16) {
            float4 v0 = fea4[(size_t)a * 32 + fc];
            float4 v1 = fea4[(size_t)(a + 8) * 32 + fc];
            acc0.x += v0.x; acc0.y += v0.y; acc0.z += v0.z; acc0.w += v0.w;
            acc1.x += v1.x; acc1.y += v1.y; acc1.z += v1.z; acc1.w += v1.w;
        }
        if (a < re) {
            float4 v = fea4[(size_t)a * 32 + fc];
            acc0.x += v.x; acc0.y += v.y; acc0.z += v.z; acc0.w += v.w;
        }
        acc0.x += acc1.x; acc0.y += acc1.y; acc0.z += acc1.z; acc0.w += acc1.w;

        red4[al][fc] = acc0;
        __syncthreads();
        if (tid < NFEA) {
            const float* redf = (const float*)red4;   // [8][128]
            float ssum = 0.f;
            #pragma unroll
            for (int g = 0; g < 8; ++g) ssum += redf[g * NFEA + tid];
            atomicAdd(&seg_sum[(size_t)s * NFEA + tid], ssum);
        }
        __syncthreads();
        rs = re; ++s;
    }
}

// Kernel B: one 64-lane wave per crystal: mean -> LN -> softplus -> head.
__global__ __launch_bounds__(64) void finalize_kernel(
    const float* __restrict__ seg_sum,  // [N_CRYS][128]
    const int2*  __restrict__ idx,
    const float* __restrict__ lnw,
    const float* __restrict__ lnb,
    const float* __restrict__ outw,     // [5][128]
    const float* __restrict__ outb,     // [5]
    float* __restrict__ out_cls,        // [N_CRYS][5]
    float* __restrict__ out_act)        // [N_CRYS][128]
{
    const int c   = blockIdx.x;
    const int tid = threadIdx.x;
    const int2 se = idx[c];
    const float inv_len = 1.f / (float)(se.y - se.x);

    float p0 = seg_sum[(size_t)c * NFEA + tid]      * inv_len;
    float p1 = seg_sum[(size_t)c * NFEA + tid + 64] * inv_len;

    float t = p0 + p1;
    #pragma unroll
    for (int off = 32; off; off >>= 1) t += __shfl_xor(t, off);
    const float mu = t * (1.f / NFEA);

    const float d0 = p0 - mu, d1 = p1 - mu;
    float v = d0 * d0 + d1 * d1;
    #pragma unroll
    for (int off = 32; off; off >>= 1) v += __shfl_xor(v, off);
    const float rstd = rsqrtf(v * (1.f / NFEA) + LN_EPS);

    const float x0 = d0 * rstd * lnw[tid]      + lnb[tid];
    const float x1 = d1 * rstd * lnw[tid + 64] + lnb[tid + 64];
    const float a0 = (x0 > 0.f) ? x0 + log1pf(expf(-x0)) : log1pf(expf(x0));
    const float a1 = (x1 > 0.f) ? x1 + log1pf(expf(-x1)) : log1pf(expf(x1));

    out_act[(size_t)c * NFEA + tid]      = a0;
    out_act[(size_t)c * NFEA + tid + 64] = a1;

    #pragma unroll
    for (int k = 0; k < NCLS; ++k) {
        float p = a0 * outw[k * NFEA + tid] + a1 * outw[k * NFEA + tid + 64];
        #pragma unroll
        for (int off = 32; off; off >>= 1) p += __shfl_xor(p, off);
        if (tid == k) out_cls[(size_t)c * NCLS + k] = p + outb[k];
    }
}

extern "C" void kernel_launch(void* const* d_in, const int* in_sizes, int n_in,
                              void* d_out, int out_size, void* d_ws, size_t ws_size,
                              hipStream_t stream) {
    const float* fea  = (const float*)d_in[0];   // [1048576][128] f32
    const int2*  idx  = (const int2*)d_in[1];    // [8192][2] i32
    const float* lnw  = (const float*)d_in[2];
    const float* lnb  = (const float*)d_in[3];
    const float* outw = (const float*)d_in[4];
    const float* outb = (const float*)d_in[5];

    const int n_crys  = in_sizes[1] / 2;         // 8192
    const int n_atoms = in_sizes[0] / NFEA;      // 1048576

    float* seg_sum = (float*)d_ws;               // [n_crys][128] partials
    float* out_cls = (float*)d_out;                          // 8192*5
    float* out_act = (float*)d_out + (size_t)n_crys * NCLS;  // 8192*128

    hipMemsetAsync(seg_sum, 0, (size_t)n_crys * NFEA * sizeof(float), stream);

    seg_partial_kernel<<<n_atoms / CHUNK, 256, 0, stream>>>(fea, idx, seg_sum, n_crys);
    finalize_kernel<<<n_crys, 64, 0, stream>>>(seg_sum, idx, lnw, lnb, outw, outb,
                                               out_cls, out_act);
}